// Round 15
// baseline (145.221 us; speedup 1.0000x reference)
//
#include <hip/hip_runtime.h>
#include <hip/hip_bf16.h>
#include <stdint.h>

typedef unsigned short ushort_t;
typedef short v8s __attribute__((ext_vector_type(8)));
typedef float f32x4 __attribute__((ext_vector_type(4)));
typedef float f32x16 __attribute__((ext_vector_type(16)));

#define MFMA16(a, b, c) __builtin_amdgcn_mfma_f32_16x16x32_bf16(a, b, c, 0, 0, 0)
#define MFMA32(a, b, c) __builtin_amdgcn_mfma_f32_32x32x16_bf16(a, b, c, 0, 0, 0)

typedef __attribute__((address_space(1))) void gvoid;
typedef __attribute__((address_space(3))) void svoid;

__device__ __forceinline__ void gld16(const void* g, void* s) {
    __builtin_amdgcn_global_load_lds((gvoid*)g, (svoid*)s, 16, 0, 0);
}

__device__ __forceinline__ ushort_t f2bf(float f) {
    union { __hip_bfloat16 b; ushort_t u; } c;
    c.b = __float2bfloat16(f);
    return c.u;
}

__device__ __forceinline__ unsigned f2bf2(float a, float b) {
    union { __hip_bfloat162 b2; unsigned u; } c;
    c.b2 = __float22bfloat162_rn(make_float2(a, b));
    return c.u;
}

__device__ __forceinline__ f32x16 zero16() {
    f32x16 z;
    #pragma unroll
    for (int i = 0; i < 16; i++) z[i] = 0.f;
    return z;
}

// ---------------------------------------------------------------------------
// Kernel 1: W [2048][128] f32 -> WT [384][2048] bf16 row-major (fallback path)
//           AND WB blocked: (d>>5)*65536 + (K>>4)*512 + ((K>>3)&1)*256
//                         + (d&31)*8 + (K&7)   (same frag layout as x_blk)
// ---------------------------------------------------------------------------
__global__ void transpose_w(const float* __restrict__ Wq, const float* __restrict__ Wk,
                            const float* __restrict__ Wv, ushort_t* __restrict__ WT,
                            ushort_t* __restrict__ WB) {
    __shared__ float tile[64][132];
    int bid = blockIdx.x;            // 96 = 3 weights x 32 k-blocks
    int w = bid >> 5;
    int k0 = (bid & 31) << 6;
    const float* W = (w == 0) ? Wq : ((w == 1) ? Wk : Wv);
    int tid = threadIdx.x;
    #pragma unroll
    for (int i = 0; i < 8; i++) {
        int row = i * 8 + (tid >> 5);
        int col = (tid & 31) * 4;
        float4 v = *(const float4*)(W + (size_t)(k0 + row) * 128 + col);
        tile[row][col] = v.x; tile[row][col + 1] = v.y;
        tile[row][col + 2] = v.z; tile[row][col + 3] = v.w;
    }
    __syncthreads();
    int n = tid >> 1, kh = (tid & 1) * 32;
    int dg = w * 128 + n;
    // row-major WT (fallback proj)
    ushort_t* dst = WT + (size_t)dg * 2048 + k0 + kh;
    #pragma unroll
    for (int j = 0; j < 32; j += 4) {
        union { ushort_t u[4]; uint2 v2; } pk;
        #pragma unroll
        for (int e = 0; e < 4; e++) pk.u[e] = f2bf(tile[kh + j + e][n]);
        *(uint2*)(dst + j) = pk.v2;
    }
    // blocked WB
    ushort_t* db = WB + (size_t)(dg >> 5) * 65536 + (dg & 31) * 8;
    #pragma unroll
    for (int o = 0; o < 4; o++) {
        int K = k0 + kh + o * 8;
        union { ushort_t u[8]; v8s v; } pk8;
        #pragma unroll
        for (int e = 0; e < 8; e++) pk8.u[e] = f2bf(tile[kh + o * 8 + e][n]);
        *(v8s*)(db + (size_t)(K >> 4) * 512 + ((K >> 3) & 1) * 256) = pk8.v;
    }
}

// ---------------------------------------------------------------------------
// Kernel 1b: xconvert — x [16384][2048] f32 -> x_blk bf16, blocked layout
//   (t>>5)*65536 + (K>>4)*512 + ((K>>3)&1)*256 + (t&31)*8 + (K&7)
// Streaming: coalesced f32x4 read -> cvt -> LDS (blocked order) -> 1KB writes.
// grid 512 (one 32-row t-tile per block), 4 chunks of K=512 each.
// ---------------------------------------------------------------------------
__launch_bounds__(256, 2)
__global__ void xconvert(const float* __restrict__ x, ushort_t* __restrict__ xb) {
    __shared__ ushort_t lbuf[16384];   // 32 KB, holds one chunk in final order
    int tt = blockIdx.x;
    int tid = threadIdx.x;
    const float* xs = x + (size_t)tt * 32 * 2048;
    ushort_t* xd = xb + (size_t)tt * 65536;
    for (int c = 0; c < 4; c++) {
        if (c) __syncthreads();
        #pragma unroll
        for (int j = 0; j < 16; j++) {
            int f = tid + j * 256;          // f32x4 index 0..4095
            int row = f >> 7;
            int kl = (f & 127) * 4;
            float4 v = *(const float4*)(xs + (size_t)row * 2048 + c * 512 + kl);
            uint2 p;
            p.x = f2bf2(v.x, v.y);
            p.y = f2bf2(v.z, v.w);
            *(uint2*)(lbuf + (kl >> 4) * 512 + ((kl >> 3) & 1) * 256 + row * 8 + (kl & 7)) = p;
        }
        __syncthreads();
        #pragma unroll
        for (int j = 0; j < 8; j++) {
            int off = tid * 8 + j * 2048;
            *(v8s*)(xd + c * 16384 + off) = *(const v8s*)(lbuf + off);
        }
    }
}

// ---------------------------------------------------------------------------
// Kernel 2: proj_blk — attn-style register-direct GEMM. ZERO LDS, ZERO
// barriers. out[t][d] = x[t][:]·W[:,d] via MFMA32(A=W-frag, B=x-frag)
// (orientation verified by attn: col=lane&31 = B-row (t), row=crow = A-row (d)).
// grid 512 = 8 xcd x 16 tblocks x 4 dblocks; block = 128t x 96d, 6 waves
// (dw 0..2 x th 0..1): wave = 32d x 64t (2 t-tiles), acc 2 x f32x16.
// k-loop: 32 chunks of k64, 2-deep ping-pong register prefetch; every load
// is a contiguous 1KB wave instruction from the blocked layouts.
// ---------------------------------------------------------------------------
#define PB_LOAD(WF, XA, XB2, C)                                               \
    {                                                                         \
        _Pragma("unroll")                                                     \
        for (int j = 0; j < 4; j++) WF[j]  = *(const v8s*)(wg  + ((C) * 4 + j) * 512); \
        _Pragma("unroll")                                                     \
        for (int j = 0; j < 4; j++) XA[j]  = *(const v8s*)(xg0 + ((C) * 4 + j) * 512); \
        _Pragma("unroll")                                                     \
        for (int j = 0; j < 4; j++) XB2[j] = *(const v8s*)(xg1 + ((C) * 4 + j) * 512); \
    }

#define PB_STEP(WF, XA, XB2)                                                  \
    {                                                                         \
        __builtin_amdgcn_s_setprio(1);                                        \
        _Pragma("unroll")                                                     \
        for (int j = 0; j < 4; j++) {                                         \
            acc0 = MFMA32(WF[j], XA[j], acc0);                                \
            acc1 = MFMA32(WF[j], XB2[j], acc1);                               \
        }                                                                     \
        __builtin_amdgcn_s_setprio(0);                                        \
    }

__launch_bounds__(384, 3)
__global__ void proj_blk(const ushort_t* __restrict__ xb, const ushort_t* __restrict__ wb,
                         ushort_t* __restrict__ q, ushort_t* __restrict__ kb,
                         ushort_t* __restrict__ vb) {
    int bid = blockIdx.x;
    int xcd = bid & 7, idx = bid >> 3;
    int dblk = idx & 3, tbl = idx >> 2;           // 4 dblocks x 16 tblocks/xcd
    int tb = (xcd * 16 + tbl) * 128;              // t-base (128 rows)
    int tid = threadIdx.x, lane = tid & 63, wid = tid >> 6;   // wid 0..5
    int dw = wid % 3, th = wid / 3;               // 3 d-waves x 2 t-halves
    int d0 = dblk * 96 + dw * 32;
    int hi = lane >> 5, lo = lane & 31;

    const ushort_t* xg0 = xb + (size_t)((tb >> 5) + th * 2) * 65536 + lane * 8;
    const ushort_t* xg1 = xg0 + 65536;
    const ushort_t* wg  = wb + (size_t)(d0 >> 5) * 65536 + lane * 8;

    f32x16 acc0 = zero16(), acc1 = zero16();
    v8s wfA[4], xaA[4], xbA[4], wfB[4], xaB[4], xbB[4];

    PB_LOAD(wfA, xaA, xbA, 0);
    for (int c = 0; c < 30; c += 2) {
        PB_LOAD(wfB, xaB, xbB, c + 1);
        PB_STEP(wfA, xaA, xbA);
        PB_LOAD(wfA, xaA, xbA, c + 2);
        PB_STEP(wfB, xaB, xbB);
    }
    PB_LOAD(wfB, xaB, xbB, 31);
    PB_STEP(wfA, xaA, xbA);
    PB_STEP(wfB, xaB, xbB);

    // epilogue: value[r] = out[t = ttile*32 + lo][d = d0 + (r&3)+8*(r>>2)+4*hi]
    int w = d0 >> 7;                  // 0=q, 1=k, 2=v (tile never straddles)
    int ddb = d0 & 127;
    size_t bbase = (size_t)(tb >> 12) * 524288;
    int tloc = (tb & 4095) + th * 64;
    #pragma unroll
    for (int tt2 = 0; tt2 < 2; tt2++) {
        f32x16 A = tt2 ? acc1 : acc0;
        int ttile = (tloc >> 5) + tt2;
        if (w < 2) {
            ushort_t* dst = (w == 0) ? q : kb;
            size_t tbase = bbase + (size_t)ttile * 4096 + lo * 8;
            #pragma unroll
            for (int r = 0; r < 16; r++) {
                int d = ddb + (r & 3) + 8 * (r >> 2) + 4 * hi;
                dst[tbase + (d >> 4) * 512 + ((d >> 3) & 1) * 256 + (d & 7)] = f2bf(A[r]);
            }
        } else {
            int t = ttile * 32 + lo;
            size_t tbase = bbase + (size_t)(t >> 4) * 2048 + ((t >> 3) & 1) * 256 + (t & 7);
            #pragma unroll
            for (int r = 0; r < 16; r++) {
                int d = ddb + (r & 3) + 8 * (r >> 2) + 4 * hi;
                vb[tbase + (d >> 5) * 512 + (d & 31) * 8] = f2bf(A[r]);
            }
        }
    }
}

// ---------------------------------------------------------------------------
// Kernel 2-FALLBACK (small ws): R13 proj — 128m x 192n, m201-style phases.
// ---------------------------------------------------------------------------
#define PJ_XLOAD(S, IT)                                                       \
    {                                                                         \
        _Pragma("unroll")                                                     \
        for (int i = 0; i < 4; i++)                                           \
            S[i] = *(const f32x4*)(xsrc[i] + (size_t)(IT) * 256);             \
    }

#define PJ_CVT_WRITE(RS, PAR)                                                 \
    {                                                                         \
        _Pragma("unroll")                                                     \
        for (int i = 0; i < 4; i++) {                                         \
            uint2 p;                                                          \
            p.x = f2bf2(RS[i][0], RS[i][1]);                                  \
            p.y = f2bf2(RS[i][2], RS[i][3]);                                  \
            *(uint2*)((char*)abuf + (PAR) * 16384 + awb[i]) = p;              \
        }                                                                     \
    }

#define PJ_PHASE1(PAR, IT, DOB)                                               \
    {                                                                         \
        const char* ab = (const char*)abuf + (PAR) * 16384;                   \
        const char* bb = (const char*)bbuf + (PAR) * 24576;                   \
        v8s af[4], bf[3];                                                     \
        _Pragma("unroll")                                                     \
        for (int m = 0; m < 4; m++) {                                         \
            int row = wr * 64 + m * 16 + lr;                                  \
            af[m] = *(const v8s*)(ab + row * 128 + ((lg * 16) ^ ((row & 7) << 4))); \
        }                                                                     \
        _Pragma("unroll")                                                     \
        for (int n = 0; n < 3; n++) {                                         \
            int row = wc * 48 + n * 16 + lr;                                  \
            bf[n] = *(const v8s*)(bb + row * 128 + ((lg * 16) ^ ((row & 7) << 4))); \
        }                                                                     \
        __builtin_amdgcn_sched_barrier(0);                                    \
        if (DOB) {                                                            \
            _Pragma("unroll")                                                 \
            for (int i = 0; i < 3; i++)                                       \
                gld16(bsrc[i] + (size_t)((IT) + 1) * 128,                     \
                      (char*)bbuf + ((PAR) ^ 1) * 24576 + (wid * 3 + i) * 1024); \
        }                                                                     \
        __builtin_amdgcn_sched_barrier(0);                                    \
        __builtin_amdgcn_s_barrier();                                         \
        asm volatile("s_waitcnt lgkmcnt(0)" ::: "memory");                    \
        __builtin_amdgcn_sched_barrier(0);                                    \
        __builtin_amdgcn_s_setprio(1);                                        \
        _Pragma("unroll")                                                     \
        for (int m = 0; m < 4; m++)                                           \
            _Pragma("unroll")                                                 \
            for (int n = 0; n < 3; n++)                                       \
                acc[m][n] = MFMA16(af[m], bf[n], acc[m][n]);                  \
        __builtin_amdgcn_s_setprio(0);                                        \
        __builtin_amdgcn_s_barrier();                                         \
    }

#define PJ_PHASE2(PAR, IT, RLOAD, RCVT, DOX, DOB)                             \
    {                                                                         \
        const char* ab = (const char*)abuf + (PAR) * 16384;                   \
        const char* bb = (const char*)bbuf + (PAR) * 24576;                   \
        v8s af[4], bf[3];                                                     \
        _Pragma("unroll")                                                     \
        for (int m = 0; m < 4; m++) {                                         \
            int row = wr * 64 + m * 16 + lr;                                  \
            af[m] = *(const v8s*)(ab + row * 128 + ((64 + lg * 16) ^ ((row & 7) << 4))); \
        }                                                                     \
        _Pragma("unroll")                                                     \
        for (int n = 0; n < 3; n++) {                                         \
            int row = wc * 48 + n * 16 + lr;                                  \
            bf[n] = *(const v8s*)(bb + row * 128 + ((64 + lg * 16) ^ ((row & 7) << 4))); \
        }                                                                     \
        __builtin_amdgcn_sched_barrier(0);                                    \
        if (DOX) PJ_XLOAD(RLOAD, (IT) + 2);                                   \
        __builtin_amdgcn_sched_barrier(0);                                    \
        if (DOB) PJ_CVT_WRITE(RCVT, (PAR) ^ 1);                               \
        __builtin_amdgcn_sched_barrier(0);                                    \
        if (DOB) {                                                            \
            if (DOX) { asm volatile("s_waitcnt vmcnt(4)" ::: "memory"); }     \
            else     { asm volatile("s_waitcnt vmcnt(0)" ::: "memory"); }     \
        }                                                                     \
        __builtin_amdgcn_s_barrier();                                         \
        asm volatile("s_waitcnt lgkmcnt(0)" ::: "memory");                    \
        __builtin_amdgcn_sched_barrier(0);                                    \
        __builtin_amdgcn_s_setprio(1);                                        \
        _Pragma("unroll")                                                     \
        for (int m = 0; m < 4; m++)                                           \
            _Pragma("unroll")                                                 \
            for (int n = 0; n < 3; n++)                                       \
                acc[m][n] = MFMA16(af[m], bf[n], acc[m][n]);                  \
        __builtin_amdgcn_s_setprio(0);                                        \
        __builtin_amdgcn_s_barrier();                                         \
    }

#define PJ_TILE(PAR, IT, RLOAD, RCVT, DOX, DOB)                               \
    PJ_PHASE1(PAR, IT, DOB)                                                   \
    PJ_PHASE2(PAR, IT, RLOAD, RCVT, DOX, DOB)

__launch_bounds__(512, 1)
__global__ void proj_fb(const float* __restrict__ x, const ushort_t* __restrict__ WT,
                        ushort_t* __restrict__ q, ushort_t* __restrict__ kb,
                        ushort_t* __restrict__ vb) {
    __shared__ ushort_t abuf[2][8192];
    __shared__ ushort_t bbuf[2][12288];

    int bid = blockIdx.x;
    int xcd = bid & 7, t2 = bid >> 3;
    int nh = t2 & 1, mtl = t2 >> 1;
    int mtile = xcd * 16 + mtl;
    size_t m0 = (size_t)mtile * 128;
    int c0 = nh * 192;
    int tid = threadIdx.x, lane = tid & 63, wid = tid >> 6;
    int lg = lane >> 4, lr = lane & 15;
    int wr = wid >> 2, wc = wid & 3;

    f32x4 acc[4][3];
    #pragma unroll
    for (int m = 0; m < 4; m++)
        #pragma unroll
        for (int n = 0; n < 3; n++) acc[m][n] = (f32x4){0.f, 0.f, 0.f, 0.f};

    const char* xsrc[4];
    int awb[4];
    #pragma unroll
    for (int i = 0; i < 4; i++) {
        int row = 16 * wid + 4 * i + (lane >> 4);
        xsrc[i] = (const char*)x + (m0 + row) * 8192 + (lane & 15) * 16;
        awb[i] = row * 128 + (((lane & 15) * 8) ^ ((row & 7) << 4));
    }
    const char* bsrc[3];
    #pragma unroll
    for (int i = 0; i < 3; i++) {
        int row = 8 * (3 * wid + i) + (lane >> 3);
        int col = ((lane & 7) * 16) ^ ((row & 7) << 4);
        bsrc[i] = (const char*)WT + (size_t)(c0 + row) * 4096 + col;
    }

    f32x4 xs0[4], xs1[4];
    #pragma unroll
    for (int i = 0; i < 3; i++)
        gld16(bsrc[i], (char*)bbuf + (wid * 3 + i) * 1024);
    PJ_XLOAD(xs0, 0);
    PJ_XLOAD(xs1, 1);
    PJ_CVT_WRITE(xs0, 0);
    asm volatile("s_waitcnt vmcnt(0)" ::: "memory");
    asm volatile("s_waitcnt lgkmcnt(0)" ::: "memory");
    __builtin_amdgcn_s_barrier();

    for (int t = 0; t < 30; t += 2) {
        PJ_TILE(0, t,     xs0, xs1, 1, 1);
        PJ_TILE(1, t + 1, xs1, xs0, 1, 1);
    }
    PJ_TILE(0, 30, xs0, xs1, 0, 1);
    PJ_TILE(1, 31, xs1, xs0, 0, 0);

    #pragma unroll
    for (int m = 0; m < 4; m++) {
        #pragma unroll
        for (int e = 0; e < 4; e++) {
            size_t row = m0 + (size_t)(wr * 64 + m * 16 + 4 * lg + e);
            int t = (int)(row & 4095);
            size_t base = (row >> 12) * 524288;
            #pragma unroll
            for (int n = 0; n < 3; n++) {
                int col = c0 + wc * 48 + n * 16 + lr;
                int w = col >> 7, d = col & 127;
                ushort_t val = f2bf(acc[m][n][e]);
                if (w == 0)
                    q[base + (size_t)(t >> 5) * 4096 + (d >> 4) * 512 + ((d >> 3) & 1) * 256 + (t & 31) * 8 + (d & 7)] = val;
                else if (w == 1)
                    kb[base + (size_t)(t >> 5) * 4096 + (d >> 4) * 512 + ((d >> 3) & 1) * 256 + (t & 31) * 8 + (d & 7)] = val;
                else
                    vb[base + (size_t)(t >> 4) * 2048 + (d >> 5) * 512 + ((t >> 3) & 1) * 256 + (d & 31) * 8 + (t & 7)] = val;
            }
        }
    }
}

// ---------------------------------------------------------------------------
// Kernel 3: causal flash attention (UNCHANGED — ~17-19 µs, ~900 TF effective).
// ---------------------------------------------------------------------------
#define ATT_PVC(SV, BASE, VC, CNEXT)                                          \
    {                                                                         \
        unsigned a0 = f2bf2(SV[(BASE) + 0], SV[(BASE) + 1]);                  \
        unsigned a1 = f2bf2(SV[(BASE) + 2], SV[(BASE) + 3]);                  \
        unsigned b0 = f2bf2(SV[(BASE) + 4], SV[(BASE) + 5]);                  \
        unsigned b1 = f2bf2(SV[(BASE) + 6], SV[(BASE) + 7]);                  \
        unsigned snd0 = hi ? a0 : b0, snd1 = hi ? a1 : b1;                    \
        unsigned rcv0 = (unsigned)__shfl_xor((int)snd0, 32);                  \
        unsigned rcv1 = (unsigned)__shfl_xor((int)snd1, 32);                  \
        union { unsigned u[4]; v8s v; } pf;                                   \
        pf.u[0] = hi ? rcv0 : a0;                                             \
        pf.u[1] = hi ? rcv1 : a1;                                             \
        pf.u[2] = hi ? b0 : rcv0;                                             \
        pf.u[3] = hi ? b1 : rcv1;                                             \
        __builtin_amdgcn_s_setprio(1);                                        \
        _Pragma("unroll")                                                     \
        for (int dt = 0; dt < 4; dt++)                                        \
            accO[dt] = MFMA32(VC[dt], pf.v, accO[dt]);                        \
        __builtin_amdgcn_s_setprio(0);                                        \
        if ((CNEXT) >= 0) {                                                   \
            _Pragma("unroll")                                                 \
            for (int dt = 0; dt < 4; dt++)                                    \
                VC[dt] = *(const v8s*)(vg + (CNEXT) * 2048 + dt * 512);       \
        }                                                                     \
    }

__launch_bounds__(256, 2)
__global__ void attn_kernel(const ushort_t* __restrict__ q, const ushort_t* __restrict__ kb,
                            const ushort_t* __restrict__ vb, float* __restrict__ out) {
    __shared__ float obuf[4][4][16][64];
    __shared__ float stat[2][4][64];

    int bid = blockIdx.x;
    int xcd = bid & 7, rk = bid >> 3;
    int b = xcd >> 1;
    int g = rk * 2 + (xcd & 1);
    int qt = (g & 1) ? (g >> 1) : (127 - (g >> 1));
    int qt0 = qt * 32;
    int tid = threadIdx.x, lane = tid & 63, wid = tid >> 6;
    int hi = lane >> 5, lo = lane & 31;
    size_t bb = (size_t)b * 524288;
    int nt = (qt >> 1) + 1;
    const float cexp = 0.08838834764831845f * 1.4426950408889634f;

    v8s qf[8];
    {
        const ushort_t* qg = q + bb + (size_t)qt * 4096 + (size_t)lane * 8;
        #pragma unroll
        for (int ks = 0; ks < 8; ks++) qf[ks] = *(const v8s*)(qg + ks * 512);
    }

    f32x16 accO[4];
    #pragma unroll
    for (int dt = 0; dt < 4; dt++) accO[dt] = zero16();
    float mrun = -1e30f, lrun = 0.f;

    for (int t = wid; t < nt; t += 4) {
        const ushort_t* kg = kb + bb + (size_t)t * 8192 + (size_t)lane * 8;
        const ushort_t* vg = vb + bb + (size_t)t * 8192 + (size_t)lane * 8;

        f32x16 s0 = zero16(), s1 = zero16();
        __builtin_amdgcn_s_setprio(1);
        #pragma unroll
        for (int ks = 0; ks < 8; ks++) {
            v8s kf = *(const v8s*)(kg + ks * 512);
            s0 = MFMA32(kf, qf[ks], s0);
        }
        #pragma unroll
        for (int ks = 0; ks < 8; ks++) {
            v8s kf = *(const v8s*)(kg + 4096 + ks * 512);
            s1 = MFMA32(kf, qf[ks], s1);
        }
        __builtin_amdgcn_s_setprio(0);

        v8s vA[4], vB[4];
        #pragma unroll
        for (int dt = 0; dt < 4; dt++) vA[dt] = *(const v8s*)(vg + dt * 512);
        #pragma unroll
        for (int dt = 0; dt < 4; dt++) vB[dt] = *(const v8s*)(vg + 2048 + dt * 512);

        if (t == nt - 1) {
            int qrow = qt0 + lo;
            #pragma unroll
            for (int r = 0; r < 16; r++) {
                int kvb = t * 64 + (r & 3) + 8 * (r >> 2) + 4 * hi;
                if (kvb > qrow) s0[r] = -1e30f;
                if (kvb + 32 > qrow) s1[r] = -1e30f;
            }
        }

        float mx = s0[0];
        #pragma unroll
        for (int r = 1; r < 16; r++) mx = fmaxf(mx, s0[r]);
        #pragma unroll
        for (int r = 0; r < 16; r++) mx = fmaxf(mx, s1[r]);
        mx = fmaxf(mx, __shfl_xor(mx, 32));

        if (__any(mx > mrun + 62.7f)) {
            float mnew = fmaxf(mrun, mx);
            float fr = exp2f((mrun - mnew) * cexp);
            lrun *= fr;
            #pragma unroll
            for (int dt = 0; dt < 4; dt++)
                #pragma unroll
                for (int r = 0; r < 16; r++) accO[dt][r] *= fr;
            mrun = mnew;
        }
        float mc = mrun * cexp;
        float rs = 0.f;
        #pragma unroll
        for (int r = 0; r < 16; r++) { s0[r] = exp2f(fmaf(s0[r], cexp, -mc)); rs += s0[r]; }
        #pragma unroll
        for (int r = 0; r < 16; r++) { s1[r] = exp2f(fmaf(s1[r], cexp, -mc)); rs += s1[r]; }
        rs += __shfl_xor(rs, 32);
        lrun += rs;

        ATT_PVC(s0, 0, vA, 2);
        ATT_PVC(s0, 8, vB, 3);
        ATT_PVC(s1, 0, vA, -1);
        ATT_PVC(s1, 8, vB, -1);
    }

    #pragma unroll
    for (int dt = 0; dt < 4; dt++)
        #pragma unroll
        for (int r = 0; r < 16; r++)
            obuf[wid][dt][r][lane] = accO[dt][r];
    stat[0][wid][lane] = mrun;
    stat[1][wid][lane] = lrun;
    __syncthreads();

    float m0 = stat[0][0][lane], m1 = stat[0][1][lane];
    float m2 = stat[0][2][lane], m3 = stat[0][3][lane];
    float m = fmaxf(fmaxf(m0, m1), fmaxf(m2, m3));
    float f0 = exp2f((m0 - m) * cexp), f1 = exp2f((m1 - m) * cexp);
    float f2 = exp2f((m2 - m) * cexp), f3 = exp2f((m3 - m) * cexp);
    float lsum = f0 * stat[1][0][lane] + f1 * stat[1][1][lane]
               + f2 * stat[1][2][lane] + f3 * stat[1][3][lane];
    float linv = 1.0f / lsum;

    float o[16];
    #pragma unroll
    for (int r = 0; r < 16; r++)
        o[r] = (f0 * obuf[0][wid][r][lane] + f1 * obuf[1][wid][r][lane]
              + f2 * obuf[2][wid][r][lane] + f3 * obuf[3][wid][r][lane]) * linv;

    float* orow = out + ((size_t)b * 4096 + qt0 + lo) * 128 + wid * 32 + 4 * hi;
    #pragma unroll
    for (int a = 0; a < 4; a++) {
        float4 vv;
        vv.x = o[4 * a + 0]; vv.y = o[4 * a + 1];
        vv.z = o[4 * a + 2]; vv.w = o[4 * a + 3];
        *(float4*)(orow + 8 * a) = vv;
    }
}

// ---------------------------------------------------------------------------
extern "C" void kernel_launch(void* const* d_in, const int* in_sizes, int n_in,
                              void* d_out, int out_size, void* d_ws, size_t ws_size,
                              hipStream_t stream) {
    const float* x  = (const float*)d_in[0];
    const float* Wq = (const float*)d_in[1];
    const float* Wk = (const float*)d_in[2];
    const float* Wv = (const float*)d_in[3];
    float* out = (float*)d_out;
    char* ws = (char*)d_ws;

    ushort_t* q  = (ushort_t*)(ws);               // 4 MB   q_blk
    ushort_t* kb = (ushort_t*)(ws + (4u << 20));  // 4 MB   k_blk
    ushort_t* vb = (ushort_t*)(ws + (8u << 20));  // 4 MB   v_blk
    ushort_t* WT = (ushort_t*)(ws + (12u << 20)); // 1.5 MB WT row-major
    ushort_t* WB = (ushort_t*)(ws + (14u << 20)); // 1.5 MB W blocked
    ushort_t* xb = (ushort_t*)(ws + (16u << 20)); // 64 MB  x_blk bf16

    transpose_w<<<dim3(96), dim3(256), 0, stream>>>(Wq, Wk, Wv, WT, WB);
    if (ws_size >= (80ull << 20)) {
        xconvert<<<dim3(512), dim3(256), 0, stream>>>(x, xb);
        proj_blk<<<dim3(512), dim3(384), 0, stream>>>(xb, WB, q, kb, vb);
    } else {
        proj_fb<<<dim3(256), dim3(512), 0, stream>>>(x, WT, q, kb, vb);
    }
    attn_kernel<<<dim3(512), dim3(256), 0, stream>>>(q, kb, vb, out);
}